// Round 8
// baseline (285.405 us; speedup 1.0000x reference)
//
#include <hip/hip_runtime.h>
#include <hip/hip_bf16.h>
#include <stdint.h>

// ---------------------------------------------------------------------------
// O = softmax(q_n . k_n^T) @ keys_raw   (N=65536, K=4096, D=128)
// 32x32x16 MFMA, transposed scheme: S^T = Kn.Qn^T, O^T = V^T.P^T; pi folded
// into vtf packing so S^T output regs ARE the PV B-fragment after exp+pack.
// R8: D-SPLIT. grid (N/256, 2): block owns 64 q-rows/wave x 64 d-cols.
// Doubles per-wave MFMA density (16 S + 8 PV per 32-key iter, kf reused by
// two q-tiles) at 1.5x chip MFMA (S duplicated across the 2 d-splits).
// den recomputed in both splits -> no reduce pass. Barrier-free K-loop,
// operands direct from L2 blobs (L1 serves repeats: all waves same addrs).
//   knf blob: tile32 it -> byte it*8192 + ds*1024 + lane*16   (ds=0..7)
//   vtf blob: step16 sg=2it+w -> sg*4096 + (split*2+dt)*1024 + lane*16
// ws: [0,1MB) knf; [1MB,2MB) vtf.
// ---------------------------------------------------------------------------

typedef __attribute__((ext_vector_type(8))) short bf16x8;
typedef __attribute__((ext_vector_type(16))) float f32x16;

#define MFMA32(a, b, c) __builtin_amdgcn_mfma_f32_32x32x16_bf16(a, b, c, 0, 0, 0)

__device__ __forceinline__ unsigned pkbf(float lo, float hi) {
  union { __hip_bfloat162 h2; unsigned u; } v;
  v.h2 = __float22bfloat162_rn(float2{lo, hi});
  return v.u;
}

// ---------------- prep_k: fragment-pack Kn (normalized) and V^T (raw) -------
__global__ __launch_bounds__(256) void prep_k(const float* __restrict__ k,
                                              char* __restrict__ knf,
                                              char* __restrict__ vtf, int K) {
  __shared__ float sRaw[64 * 132];
  __shared__ float sScale[64];
  const int tid = threadIdx.x;
  const int kbase = blockIdx.x * 64;
  {
    const int key_loc = tid >> 2, dq = tid & 3;
    const float4* src = (const float4*)(k + (size_t)(kbase + key_loc) * 128 + dq * 32);
    float4 f[8];
    float ss = 0.f;
#pragma unroll
    for (int i = 0; i < 8; ++i) {
      f[i] = src[i];
      ss += f[i].x * f[i].x + f[i].y * f[i].y + f[i].z * f[i].z + f[i].w * f[i].w;
    }
    ss += __shfl_xor(ss, 1);
    ss += __shfl_xor(ss, 2);
    float4* dst = (float4*)(sRaw + key_loc * 132 + dq * 32);
#pragma unroll
    for (int i = 0; i < 8; ++i) dst[i] = f[i];
    if (dq == 0) sScale[key_loc] = ss > 0.f ? rsqrtf(ss) : 0.f;
  }
  __syncthreads();

  // knf: 1024 chunks of 16B per 64-key block
#pragma unroll
  for (int r = 0; r < 4; ++r) {
    const int c = r * 256 + tid;
    const int t_loc = c >> 9, ds = (c >> 6) & 7, l = c & 63;
    const int h5 = l >> 5, c32 = l & 31;
    const int key_loc = t_loc * 32 + c32;
    const float sc = sScale[key_loc];
    const float* p = sRaw + key_loc * 132 + ds * 16 + h5 * 8;
    uint4 w;
    w.x = pkbf(p[0] * sc, p[1] * sc);
    w.y = pkbf(p[2] * sc, p[3] * sc);
    w.z = pkbf(p[4] * sc, p[5] * sc);
    w.w = pkbf(p[6] * sc, p[7] * sc);
    *(uint4*)(knf + ((size_t)blockIdx.x * 1024 + c) * 16) = w;
  }
  // vtf: 1024 chunks; pi(s,h5,j) = (s>>1)*32 + (s&1)*8 + h5*4 + (j&3) + 16*(j>>2)
#pragma unroll
  for (int r = 0; r < 4; ++r) {
    const int c = r * 256 + tid;
    const int s = c >> 8, db2 = (c >> 6) & 3, l = c & 63;
    const int h5 = l >> 5, c32 = l & 31;
    const int d = db2 * 32 + c32;
    const int kb = (s >> 1) * 32 + (s & 1) * 8 + h5 * 4;
    float f[8];
#pragma unroll
    for (int j = 0; j < 8; ++j)
      f[j] = sRaw[(kb + (j & 3) + (j >> 2) * 16) * 132 + d];
    uint4 w;
    w.x = pkbf(f[0], f[1]);
    w.y = pkbf(f[2], f[3]);
    w.z = pkbf(f[4], f[5]);
    w.w = pkbf(f[6], f[7]);
    *(uint4*)(vtf + ((size_t)blockIdx.x * 1024 + c) * 16) = w;
  }
}

// ----------------------------- fused attention ------------------------------
// 256 thr = 4 waves x (64 q-rows x 64 d); grid (N/256, 2 d-splits).
__global__ __launch_bounds__(256, 2) void attn_main(
    const float* __restrict__ q, const char* __restrict__ knf,
    const char* __restrict__ vtf, float* __restrict__ out, int K) {
  __shared__ __align__(16) char sE[16384];   // wave-private epilogue scratch
  const int tid = threadIdx.x;
  const int wave = tid >> 6, lane = tid & 63;
  const int h5 = lane >> 5, c32 = lane & 31;
  const int split = blockIdx.y;              // d-half: cols split*64..+64
  const int qrow0 = blockIdx.x * 256 + wave * 64;

  // ---- Q: two q-tiles; normalize, fold log2e, pack B-fragments -------------
  bf16x8 qf[2][8];
#pragma unroll
  for (int qt = 0; qt < 2; ++qt) {
    const float* qr = q + (size_t)(qrow0 + qt * 32 + c32) * 128;
    float f[64];
    float ss = 0.f;
#pragma unroll
    for (int ds = 0; ds < 8; ++ds) {
      const float4 a = *(const float4*)(qr + ds * 16 + h5 * 8);
      const float4 b = *(const float4*)(qr + ds * 16 + h5 * 8 + 4);
      f[ds * 8 + 0] = a.x; f[ds * 8 + 1] = a.y; f[ds * 8 + 2] = a.z; f[ds * 8 + 3] = a.w;
      f[ds * 8 + 4] = b.x; f[ds * 8 + 5] = b.y; f[ds * 8 + 6] = b.z; f[ds * 8 + 7] = b.w;
    }
#pragma unroll
    for (int i = 0; i < 64; ++i) ss += f[i] * f[i];
    ss += __shfl_xor(ss, 32);
    const float sc = (ss > 0.f ? rsqrtf(ss) : 0.f) * 1.44269504f;
#pragma unroll
    for (int ds = 0; ds < 8; ++ds) {
      union { unsigned u[4]; bf16x8 v; } t;
#pragma unroll
      for (int p = 0; p < 4; ++p)
        t.u[p] = pkbf(f[ds * 8 + 2 * p] * sc, f[ds * 8 + 2 * p + 1] * sc);
      qf[qt][ds] = t.v;
    }
  }

  f32x16 acc[2][2];   // [dt][qt] : O^T 32x32 tiles
#pragma unroll
  for (int dt = 0; dt < 2; ++dt)
#pragma unroll
    for (int qt = 0; qt < 2; ++qt)
#pragma unroll
      for (int r = 0; r < 16; ++r) acc[dt][qt][r] = 0.f;
  float den[2] = {0.f, 0.f};
  f32x16 Zf;
#pragma unroll
  for (int r = 0; r < 16; ++r) Zf[r] = 0.f;

  const int nIter = K >> 5;   // 128 iters of 32 keys
  const char* vsp = vtf + split * 2048;

#pragma unroll 2
  for (int it = 0; it < nIter; ++it) {
    // kf loads (8 b128, shared by both q-tiles); issue first
    bf16x8 kf[8];
#pragma unroll
    for (int ds = 0; ds < 8; ++ds)
      kf[ds] = *(const bf16x8*)(knf + (size_t)it * 8192 + ds * 1024 + lane * 16);
    // vf loads for this tile's 2 k-steps x 2 d-tiles (4 b128)
    bf16x8 vf[2][2];
#pragma unroll
    for (int w = 0; w < 2; ++w)
#pragma unroll
      for (int dt = 0; dt < 2; ++dt)
        vf[w][dt] = *(const bf16x8*)(vsp + (size_t)(it * 2 + w) * 4096 +
                                     dt * 1024 + lane * 16);

    // ---- S^T = Kn . Qn^T : two independent chains of 8 ---------------------
    f32x16 S[2];
#pragma unroll
    for (int qt = 0; qt < 2; ++qt) {
      f32x16 s;
#pragma unroll
      for (int ds = 0; ds < 8; ++ds)
        s = MFMA32(kf[ds], qf[qt][ds], (ds == 0) ? Zf : s);
      S[qt] = s;
    }

    // ---- exp + PV: 2 k-steps of 16 keys ------------------------------------
#pragma unroll
    for (int w = 0; w < 2; ++w) {
#pragma unroll
      for (int qt = 0; qt < 2; ++qt) {
        float e[8];
#pragma unroll
        for (int j = 0; j < 8; ++j) {
          const int rr = w * 4 + (j & 3) + (j >> 2) * 8;
          e[j] = __builtin_amdgcn_exp2f(S[qt][rr]);
        }
        den[qt] += ((e[0] + e[1]) + (e[2] + e[3])) + ((e[4] + e[5]) + (e[6] + e[7]));
        union { unsigned u[4]; bf16x8 v; } pf;
#pragma unroll
        for (int j2 = 0; j2 < 4; ++j2) pf.u[j2] = pkbf(e[2 * j2], e[2 * j2 + 1]);
#pragma unroll
        for (int dt = 0; dt < 2; ++dt)
          acc[dt][qt] = MFMA32(vf[w][dt], pf.v, acc[dt][qt]);
      }
    }
  }

  float rd[2];
#pragma unroll
  for (int qt = 0; qt < 2; ++qt) {
    float d = den[qt];
    d += __shfl_xor(d, 32);
    rd[qt] = 1.0f / d;
  }

  // ---- epilogue: wave-private LDS transpose per 32x32 tile, coalesced out --
  float* wls = (float*)(sE + wave * 4096);   // 32 rows x 32 floats
#pragma unroll
  for (int dt = 0; dt < 2; ++dt)
#pragma unroll
    for (int qt = 0; qt < 2; ++qt) {
#pragma unroll
      for (int qd = 0; qd < 4; ++qd) {
        float4 v;
        v.x = acc[dt][qt][qd * 4 + 0] * rd[qt];
        v.y = acc[dt][qt][qd * 4 + 1] * rd[qt];
        v.z = acc[dt][qt][qd * 4 + 2] * rd[qt];
        v.w = acc[dt][qt][qd * 4 + 3] * rd[qt];
        *(float4*)(wls + c32 * 32 + (((h5 + 2 * qd) ^ (c32 & 7)) << 2)) = v;
      }
      // same-wave LDS write->read: compiler inserts lgkmcnt waits
#pragma unroll
      for (int p = 0; p < 4; ++p) {
        const int ql = p * 8 + (lane >> 3);
        const int x = lane & 7;
        const float4 v = *(const float4*)(wls + ql * 32 + ((x ^ (ql & 7)) << 2));
        *(float4*)(out + (size_t)(qrow0 + qt * 32 + ql) * 128 + split * 64 +
                   dt * 32 + x * 4) = v;
      }
    }
}

// ---------------------------------------------------------------------------
extern "C" void kernel_launch(void* const* d_in, const int* in_sizes, int n_in,
                              void* d_out, int out_size, void* d_ws, size_t ws_size,
                              hipStream_t stream) {
  const float* q = (const float*)d_in[0];
  const float* k = (const float*)d_in[1];
  const int N = in_sizes[0] / 128;   // 65536
  const int K = in_sizes[1] / 128;   // 4096
  char* ws = (char*)d_ws;
  char* knf = ws;                          // 1 MB
  char* vtf = ws + (size_t)K * 256;        // 1 MB
  float* out = (float*)d_out;

  prep_k<<<dim3(K / 64), dim3(256), 0, stream>>>(k, knf, vtf, K);
  attn_main<<<dim3(N / 256, 2), dim3(256), 0, stream>>>(q, knf, vtf, out, K);
}

// Round 9
// 272.519 us; speedup vs baseline: 1.0473x; 1.0473x over previous
//
#include <hip/hip_runtime.h>
#include <hip/hip_bf16.h>
#include <stdint.h>

// ---------------------------------------------------------------------------
// O = softmax(q_n . k_n^T) @ keys_raw   (N=65536, K=4096, D=128)
// 32x32x16 MFMA, transposed scheme: S^T = Kn.Qn^T, O^T = V^T.P^T; pi folded
// into vtf packing so S^T output regs ARE the PV B-fragment after exp+pack.
// R9: ANTI-PHASE SCHEDULING. Evidence r3/r5/r7/r8: time = MFMA_cyc + VALU_cyc
// + air -- the 2 waves/SIMD run identical streams and phase-lock (both in the
// S matrix burst, then both in the exp VALU burst; pipes alternate, never
// overlap). Fix: half the blocks run a ROTATED K-loop (S hoisted; body =
// exp+PV(it) then S(it+1)) so SIMD-mates sit in complementary phases.
// rot bit flips for block pairs at distance 1, 8, and 256 (covers linear and
// XCD-round-robin dispatch pairings). Also: S as 2 chains of 4 (shorter
// matrix phase, merge folded into exp input); vf single-buffered (regs~240).
//   knf blob: tile32 it -> byte it*8192 + ds*1024 + lane*16   (ds=0..7)
//   vtf blob: tile32 it -> byte it*8192 + j*1024 + lane*16    (j=w*4+db2)
// ws: [0,1MB) knf; [1MB,2MB) vtf.
// ---------------------------------------------------------------------------

typedef __attribute__((ext_vector_type(8))) short bf16x8;
typedef __attribute__((ext_vector_type(16))) float f32x16;

#define MFMA32(a, b, c) __builtin_amdgcn_mfma_f32_32x32x16_bf16(a, b, c, 0, 0, 0)

__device__ __forceinline__ unsigned pkbf(float lo, float hi) {
  union { __hip_bfloat162 h2; unsigned u; } v;
  v.h2 = __float22bfloat162_rn(float2{lo, hi});
  return v.u;
}

// ---------------- prep_k: fragment-pack Kn (normalized) and V^T (raw) -------
__global__ __launch_bounds__(256) void prep_k(const float* __restrict__ k,
                                              char* __restrict__ knf,
                                              char* __restrict__ vtf, int K) {
  __shared__ float sRaw[64 * 132];
  __shared__ float sScale[64];
  const int tid = threadIdx.x;
  const int kbase = blockIdx.x * 64;
  {
    const int key_loc = tid >> 2, dq = tid & 3;
    const float4* src = (const float4*)(k + (size_t)(kbase + key_loc) * 128 + dq * 32);
    float4 f[8];
    float ss = 0.f;
#pragma unroll
    for (int i = 0; i < 8; ++i) {
      f[i] = src[i];
      ss += f[i].x * f[i].x + f[i].y * f[i].y + f[i].z * f[i].z + f[i].w * f[i].w;
    }
    ss += __shfl_xor(ss, 1);
    ss += __shfl_xor(ss, 2);
    float4* dst = (float4*)(sRaw + key_loc * 132 + dq * 32);
#pragma unroll
    for (int i = 0; i < 8; ++i) dst[i] = f[i];
    if (dq == 0) sScale[key_loc] = ss > 0.f ? rsqrtf(ss) : 0.f;
  }
  __syncthreads();

  // knf: 1024 chunks of 16B per 64-key block
#pragma unroll
  for (int r = 0; r < 4; ++r) {
    const int c = r * 256 + tid;
    const int t_loc = c >> 9, ds = (c >> 6) & 7, l = c & 63;
    const int h5 = l >> 5, c32 = l & 31;
    const int key_loc = t_loc * 32 + c32;
    const float sc = sScale[key_loc];
    const float* p = sRaw + key_loc * 132 + ds * 16 + h5 * 8;
    uint4 w;
    w.x = pkbf(p[0] * sc, p[1] * sc);
    w.y = pkbf(p[2] * sc, p[3] * sc);
    w.z = pkbf(p[4] * sc, p[5] * sc);
    w.w = pkbf(p[6] * sc, p[7] * sc);
    *(uint4*)(knf + ((size_t)blockIdx.x * 1024 + c) * 16) = w;
  }
  // vtf: 1024 chunks; pi(s,h5,j) = (s>>1)*32 + (s&1)*8 + h5*4 + (j&3) + 16*(j>>2)
#pragma unroll
  for (int r = 0; r < 4; ++r) {
    const int c = r * 256 + tid;
    const int s = c >> 8, db2 = (c >> 6) & 3, l = c & 63;
    const int h5 = l >> 5, c32 = l & 31;
    const int d = db2 * 32 + c32;
    const int kb = (s >> 1) * 32 + (s & 1) * 8 + h5 * 4;
    float f[8];
#pragma unroll
    for (int j = 0; j < 8; ++j)
      f[j] = sRaw[(kb + (j & 3) + (j >> 2) * 16) * 132 + d];
    uint4 w;
    w.x = pkbf(f[0], f[1]);
    w.y = pkbf(f[2], f[3]);
    w.z = pkbf(f[4], f[5]);
    w.w = pkbf(f[6], f[7]);
    *(uint4*)(vtf + ((size_t)blockIdx.x * 1024 + c) * 16) = w;
  }
}

// ----------------------------- fused attention ------------------------------
// 256 thr = 4 waves x 32 q-rows; grid N/128 = 512. No __syncthreads in loop.
__global__ __launch_bounds__(256) void attn_main(
    const float* __restrict__ q, const char* __restrict__ knf,
    const char* __restrict__ vtf, float* __restrict__ out, int K) {
  __shared__ __align__(16) char sE[16384];   // wave-private epilogue scratch
  const int tid = threadIdx.x;
  const int wave = tid >> 6, lane = tid & 63;
  const int h5 = lane >> 5, c32 = lane & 31;
  const int qrow0 = blockIdx.x * 128 + wave * 32;

  // ---- Q: load row (qrow0+c32), normalize, fold log2e, pack B-fragments ---
  bf16x8 qf[8];
  {
    const float* qr = q + (size_t)(qrow0 + c32) * 128;
    float f[64];
    float ss = 0.f;
#pragma unroll
    for (int ds = 0; ds < 8; ++ds) {
      const float4 a = *(const float4*)(qr + ds * 16 + h5 * 8);
      const float4 b = *(const float4*)(qr + ds * 16 + h5 * 8 + 4);
      f[ds * 8 + 0] = a.x; f[ds * 8 + 1] = a.y; f[ds * 8 + 2] = a.z; f[ds * 8 + 3] = a.w;
      f[ds * 8 + 4] = b.x; f[ds * 8 + 5] = b.y; f[ds * 8 + 6] = b.z; f[ds * 8 + 7] = b.w;
    }
#pragma unroll
    for (int i = 0; i < 64; ++i) ss += f[i] * f[i];
    ss += __shfl_xor(ss, 32);
    const float sc = (ss > 0.f ? rsqrtf(ss) : 0.f) * 1.44269504f;
#pragma unroll
    for (int ds = 0; ds < 8; ++ds) {
      union { unsigned u[4]; bf16x8 v; } t;
#pragma unroll
      for (int p = 0; p < 4; ++p)
        t.u[p] = pkbf(f[ds * 8 + 2 * p] * sc, f[ds * 8 + 2 * p + 1] * sc);
      qf[ds] = t.v;
    }
  }

  f32x16 acc[4];
#pragma unroll
  for (int db2 = 0; db2 < 4; ++db2)
#pragma unroll
    for (int r = 0; r < 16; ++r) acc[db2][r] = 0.f;
  float den = 0.f;
  f32x16 Zf;
#pragma unroll
  for (int r = 0; r < 16; ++r) Zf[r] = 0.f;

  const int nIter = K >> 5;   // 128 iters of 32 keys

  auto loadK = [&](int it, bf16x8 (&kf)[8]) {
    if (it >= nIter) it = nIter - 1;
#pragma unroll
    for (int ds = 0; ds < 8; ++ds)
      kf[ds] = *(const bf16x8*)(knf + (size_t)it * 8192 + ds * 1024 + lane * 16);
  };
  auto loadV = [&](int it, bf16x8 (&vf)[8]) {
#pragma unroll
    for (int j = 0; j < 8; ++j)
      vf[j] = *(const bf16x8*)(vtf + (size_t)it * 8192 + j * 1024 + lane * 16);
  };
  // S^T = Kn.Qn^T as two independent chains of 4 (merge folded into exp)
  auto computeS = [&](const bf16x8 (&kf)[8], f32x16& s0, f32x16& s1) {
#pragma unroll
    for (int ds = 0; ds < 4; ++ds) s0 = MFMA32(kf[ds], qf[ds], ds ? s0 : Zf);
#pragma unroll
    for (int ds = 4; ds < 8; ++ds) s1 = MFMA32(kf[ds], qf[ds], ds > 4 ? s1 : Zf);
  };
  // exp(s0+s1) -> pf -> PV (2 k-steps of 16 keys)
  auto expPV = [&](const bf16x8 (&vf)[8], const f32x16& s0, const f32x16& s1) {
#pragma unroll
    for (int w = 0; w < 2; ++w) {
      float e[8];
#pragma unroll
      for (int j = 0; j < 8; ++j) {
        const int rr = w * 4 + (j & 3) + (j >> 2) * 8;
        e[j] = __builtin_amdgcn_exp2f(s0[rr] + s1[rr]);
      }
      den += ((e[0] + e[1]) + (e[2] + e[3])) + ((e[4] + e[5]) + (e[6] + e[7]));
      union { unsigned u[4]; bf16x8 v; } pf;
#pragma unroll
      for (int j2 = 0; j2 < 4; ++j2) pf.u[j2] = pkbf(e[2 * j2], e[2 * j2 + 1]);
#pragma unroll
      for (int db2 = 0; db2 < 4; ++db2)
        acc[db2] = MFMA32(vf[w * 4 + db2], pf.v, acc[db2]);
    }
  };

  // Anti-phase bit: flips for block pairs at distance 1, 8, and 256 so the
  // two blocks co-resident on a CU (whatever the dispatch pairing) run in
  // complementary phases on their shared SIMDs.
  const int rot = (blockIdx.x ^ (blockIdx.x >> 3) ^ (blockIdx.x >> 8)) & 1;

  bf16x8 kfA[8], kfB[8], vfS[8];
  f32x16 s0, s1;
  if (!rot) {
    // straight: [ S(it) | exp,PV(it) ]
    loadK(0, kfA);
    for (int it = 0; it < nIter; it += 2) {
      loadK(it + 1, kfB);
      computeS(kfA, s0, s1);
      loadV(it, vfS);
      expPV(vfS, s0, s1);
      loadK(it + 2, kfA);
      computeS(kfB, s0, s1);
      loadV(it + 1, vfS);
      expPV(vfS, s0, s1);
    }
  } else {
    // rotated: S hoisted; body = [ exp,PV(it) | S(it+1) ]
    loadK(0, kfA);
    computeS(kfA, s0, s1);
    for (int it = 0; it < nIter - 1; ++it) {
      loadK(it + 1, kfA);          // kf of tile it is dead (S already done)
      loadV(it, vfS);
      expPV(vfS, s0, s1);          // tile it
      computeS(kfA, s0, s1);       // tile it+1
    }
    loadV(nIter - 1, vfS);
    expPV(vfS, s0, s1);
  }

  den += __shfl_xor(den, 32);
  const float rd = 1.0f / den;

  // ---- epilogue: wave-private LDS transpose (no barrier), coalesced out ----
  float* wls = (float*)(sE + wave * 4096);   // 32 q-rows x 32 floats
#pragma unroll
  for (int db2 = 0; db2 < 4; ++db2) {
#pragma unroll
    for (int qd = 0; qd < 4; ++qd) {
      float4 v;
      v.x = acc[db2][qd * 4 + 0] * rd;
      v.y = acc[db2][qd * 4 + 1] * rd;
      v.z = acc[db2][qd * 4 + 2] * rd;
      v.w = acc[db2][qd * 4 + 3] * rd;
      *(float4*)(wls + c32 * 32 + (((h5 + 2 * qd) ^ (c32 & 7)) << 2)) = v;
    }
    // same-wave LDS write->read: compiler inserts lgkmcnt waits
#pragma unroll
    for (int p = 0; p < 4; ++p) {
      const int ql = p * 8 + (lane >> 3);
      const int x = lane & 7;
      const float4 v = *(const float4*)(wls + ql * 32 + ((x ^ (ql & 7)) << 2));
      *(float4*)(out + (size_t)(qrow0 + ql) * 128 + db2 * 32 + x * 4) = v;
    }
  }
}

// ---------------------------------------------------------------------------
extern "C" void kernel_launch(void* const* d_in, const int* in_sizes, int n_in,
                              void* d_out, int out_size, void* d_ws, size_t ws_size,
                              hipStream_t stream) {
  const float* q = (const float*)d_in[0];
  const float* k = (const float*)d_in[1];
  const int N = in_sizes[0] / 128;   // 65536
  const int K = in_sizes[1] / 128;   // 4096
  char* ws = (char*)d_ws;
  char* knf = ws;                          // 1 MB
  char* vtf = ws + (size_t)K * 256;        // 1 MB
  float* out = (float*)d_out;

  prep_k<<<dim3(K / 64), dim3(256), 0, stream>>>(k, knf, vtf, K);
  attn_main<<<dim3(N / 128), dim3(256), 0, stream>>>(q, knf, vtf, out, K);
}